// Round 9
// baseline (155.078 us; speedup 1.0000x reference)
//
#include <hip/hip_runtime.h>
#include <stdint.h>

#define NN 10000      // nodes
#define NE 160000     // edges
#define NB 16         // batch
#define NT 4          // nodes per block in k_main_h (1 wave = 1 node)
// per (b,n) row: CIN*2P = 8*16 = 128 features, layout [c][t] (t fastest)

typedef __attribute__((ext_vector_type(8))) float f32x8;
typedef __attribute__((ext_vector_type(4))) float f32x4;
typedef __attribute__((ext_vector_type(2))) float f32x2;
typedef __attribute__((ext_vector_type(8))) _Float16 h16x8;

#define AGG_LD 136   // 128 + 8 pad floats per row

// edge_index may arrive as int32 (contract) or raw int64 (reference dtype).
// int64 node ids < 2^32 have all-zero high words.
__device__ __forceinline__ int ei_stride(const int* __restrict__ ei) {
    int z = ei[1] | ei[3] | ei[5] | ei[7] | ei[9] | ei[11] | ei[13] | ei[15];
    return (z == 0) ? 2 : 1;
}

// Fused prep: degree atomics + (optional) fp16 repack + folded consts.
// deg/count zeroed beforehand via hipMemsetAsync.
__global__ __launch_bounds__(256)
void k_prep(const float* __restrict__ X, h16x8* __restrict__ X2, int do_repack,
            const int* __restrict__ ei, const float* __restrict__ ew,
            float* deg, int* count,
            const float* __restrict__ attn,
            const float* __restrict__ Wcz, const float* __restrict__ bcz,
            const float* __restrict__ Wlz, const float* __restrict__ blz,
            const float* __restrict__ Wch, const float* __restrict__ bch,
            const float* __restrict__ Wlh, const float* __restrict__ blh,
            float* consts) {
    int gid = blockIdx.x * blockDim.x + threadIdx.x;
    int gsz = gridDim.x * blockDim.x;
    int stride = ei_stride(ei);
    for (int e = gid; e < NE; e += gsz) {
        int d = ei[(size_t)(NE + e) * stride];
        atomicAdd(&deg[d], ew[e]);
        atomicAdd(&count[d], 1);
    }
    if (do_repack) {
        const int total = NN * 256;
        for (int i = gid; i < total; i += gsz) {
            int n = i >> 8, t = i & 255;
            int b = t >> 4, chunk = t & 15;
            f32x8 w = ((const f32x8*)X)[((size_t)b * NN + n) * 16 + chunk];
            h16x8 h;
            #pragma unroll
            for (int j = 0; j < 8; ++j) h[j] = (_Float16)w[j];
            X2[((size_t)(b >> 1) * NN + n) * 32 + (b & 1) * 16 + chunk] = h;
        }
    }
    if (blockIdx.x == 0) {
        int tid = threadIdx.x;
        {
            int c = tid >> 5, o = tid & 31;
            float mz = 0.f, mh = 0.f;
            for (int k = 0; k < 32; ++k) {
                mz += Wcz[c * 32 + k] * Wlz[k * 32 + o];   // Wl rows 0..31 (H0 half zero)
                mh += Wch[c * 32 + k] * Wlh[k * 32 + o];
            }
            consts[tid] = mz;
            consts[256 + tid] = mh;
        }
        if (tid < 32) {
            float cz = blz[tid], ch = blh[tid];
            for (int k = 0; k < 32; ++k) {
                cz += bcz[k] * Wlz[k * 32 + tid];
                ch += bch[k] * Wlh[k * 32 + tid];
            }
            consts[512 + tid] = cz;
            consts[544 + tid] = ch;
        }
        if (tid == 0) {
            float a[16], m = -1e30f, s = 0.f;
            for (int t = 0; t < 16; ++t) { a[t] = attn[t]; m = fmaxf(m, a[t]); }
            for (int t = 0; t < 16; ++t) { a[t] = __expf(a[t] - m); s += a[t]; }
            for (int t = 0; t < 16; ++t) consts[576 + t] = a[t] / s;
        }
    }
}

// single block: exclusive scan of count -> offsets/fillptr; dinv = rsqrt(deg+1)
__global__ void k_scan(const float* __restrict__ deg, const int* __restrict__ count,
                       float* dinv, int* offsets, int* fillptr) {
    int tid = threadIdx.x;
    int lane = tid & 63, wv = tid >> 6;
    __shared__ int wsum[16];
    __shared__ int carry;
    if (tid == 0) carry = 0;
    __syncthreads();
    for (int base = 0; base < NN; base += 1024) {
        int i = base + tid;
        int v = (i < NN) ? count[i] : 0;
        int x = v;
        #pragma unroll
        for (int s = 1; s < 64; s <<= 1) {
            int y = __shfl_up(x, s, 64);
            if (lane >= s) x += y;
        }
        if (lane == 63) wsum[wv] = x;
        __syncthreads();
        if (wv == 0 && lane < 16) {
            int y = wsum[lane];
            #pragma unroll
            for (int s = 1; s < 16; s <<= 1) {
                int z = __shfl_up(y, s, 64);
                if (lane >= s) y += z;
            }
            wsum[lane] = y;
        }
        __syncthreads();
        int wbase = (wv == 0) ? 0 : wsum[wv - 1];
        int incl = carry + wbase + x;
        int excl = incl - v;
        if (i < NN) { offsets[i] = excl; fillptr[i] = excl; }
        __syncthreads();
        if (tid == 1023) carry = incl;
        __syncthreads();
    }
    for (int i = tid; i < NN; i += 1024) dinv[i] = rsqrtf(deg[i] + 1.0f);
}

// CSR fill, interleaved {src*32, norm_bits} pairs: one 64B group per 8 edges.
__global__ void k_fill(const int* __restrict__ ei, const float* __restrict__ ew,
                       const float* __restrict__ dinv,
                       int* fillptr, int* csr_sn) {
    int e = blockIdx.x * blockDim.x + threadIdx.x;
    if (e >= NE) return;
    int stride = ei_stride(ei);
    int s = ei[(size_t)e * stride];
    int d = ei[(size_t)(NE + e) * stride];
    int pos = atomicAdd(&fillptr[d], 1);
    csr_sn[2 * pos]     = s * 32;   // pre-scaled h16x8-index of the (bp,n) slice
    csr_sn[2 * pos + 1] = __float_as_int(dinv[s] * ew[e] * dinv[d]);
}

// (1-sigmoid(uz)) * tanh(uh) = (e^{2uh}-1) / ((1+e^{uz})(e^{2uh}+1))
__device__ __forceinline__ float gatefn(float uz, float uh) {
    float ez = __expf(uz);
    float eh = __expf(2.f * uh);
    return (eh - 1.f) * __builtin_amdgcn_rcpf((1.f + ez) * (eh + 1.f));
}

// Batch-partitioned gather, 1 wave = 1 node, DEPTH-4 pipeline:
// 8 edges (4 per lane-half) in flight; CSR scalars prefetched 2 groups ahead
// via s_load_dwordx16 (p/q/r rotation, compile-time indices -> SGPRs).
__global__ __launch_bounds__(256)
void k_main_h(const h16x8* __restrict__ X2,
              const int* __restrict__ offsets, const int* __restrict__ count,
              const float* __restrict__ dinv,
              const int* __restrict__ csr_sn,
              const float* __restrict__ consts,
              float* __restrict__ out) {
    __shared__ float sAgg[2 * NT * AGG_LD];   // row = node_in_tile*2 + b_local
    __shared__ float sMz[256], sMh[256], sCz[32], sCh[32], sWs[16];
    int tid = threadIdx.x;
    int bp   = blockIdx.x & 7;
    int tile = blockIdx.x >> 3;

    sMz[tid] = consts[tid];
    sMh[tid] = consts[256 + tid];
    if (tid < 32) { sCz[tid] = consts[512 + tid]; sCh[tid] = consts[544 + tid]; }
    if (tid < 16) sWs[tid] = consts[576 + tid];

    // ---- Phase A ----
    int lane = tid & 63;
    int wv = __builtin_amdgcn_readfirstlane(tid >> 6);   // wave id = node in tile
    int half = lane >> 5;
    int chunk = lane & 31;            // 16B chunk of the 512B (bp,n) slice
    int n = tile * NT + wv;
    const h16x8* xb = X2 + ((size_t)bp * NN) * 32;
    float dn = dinv[n];
    float selfn = (half == 0) ? dn * dn : 0.f;   // count self-loop once
    float acc[8];
    {
        h16x8 w = xb[(size_t)n * 32 + chunk];
        #pragma unroll
        for (int j = 0; j < 8; ++j) acc[j] = selfn * (float)w[j];
    }
    int off = __builtin_amdgcn_readfirstlane(offsets[n]);
    int cnt = __builtin_amdgcn_readfirstlane(count[n]);
    const int* snp = csr_sn + 2 * off;   // scalar base
    int e = 0;
    if (cnt >= 8) {
        int p[16], q[16], r[16];
        #pragma unroll
        for (int k = 0; k < 16; ++k) p[k] = snp[k];          // group 0 scalars
        h16x8 A0 = xb[(size_t)(half ? p[2]  : p[0])  + chunk];
        h16x8 A1 = xb[(size_t)(half ? p[6]  : p[4])  + chunk];
        h16x8 A2 = xb[(size_t)(half ? p[10] : p[8])  + chunk];
        h16x8 A3 = xb[(size_t)(half ? p[14] : p[12]) + chunk];
        #pragma unroll
        for (int k = 0; k < 16; ++k) q[k] = snp[16 + k];     // group 1 (overread ok)
        for (e = 8; e + 8 <= cnt; e += 8) {
            h16x8 B0 = xb[(size_t)(half ? q[2]  : q[0])  + chunk];
            h16x8 B1 = xb[(size_t)(half ? q[6]  : q[4])  + chunk];
            h16x8 B2 = xb[(size_t)(half ? q[10] : q[8])  + chunk];
            h16x8 B3 = xb[(size_t)(half ? q[14] : q[12]) + chunk];
            #pragma unroll
            for (int k = 0; k < 16; ++k) r[k] = snp[2 * e + 16 + k];  // next-next
            float na0 = __int_as_float(half ? p[3]  : p[1]);
            float na1 = __int_as_float(half ? p[7]  : p[5]);
            float na2 = __int_as_float(half ? p[11] : p[9]);
            float na3 = __int_as_float(half ? p[15] : p[13]);
            __builtin_amdgcn_sched_barrier(0);   // issue cluster above, consume below
            #pragma unroll
            for (int j = 0; j < 8; ++j) acc[j] += na0 * (float)A0[j];
            #pragma unroll
            for (int j = 0; j < 8; ++j) acc[j] += na1 * (float)A1[j];
            #pragma unroll
            for (int j = 0; j < 8; ++j) acc[j] += na2 * (float)A2[j];
            #pragma unroll
            for (int j = 0; j < 8; ++j) acc[j] += na3 * (float)A3[j];
            A0 = B0; A1 = B1; A2 = B2; A3 = B3;
            #pragma unroll
            for (int k = 0; k < 16; ++k) { p[k] = q[k]; q[k] = r[k]; }
        }
        {
            float na0 = __int_as_float(half ? p[3]  : p[1]);
            float na1 = __int_as_float(half ? p[7]  : p[5]);
            float na2 = __int_as_float(half ? p[11] : p[9]);
            float na3 = __int_as_float(half ? p[15] : p[13]);
            #pragma unroll
            for (int j = 0; j < 8; ++j) acc[j] += na0 * (float)A0[j];
            #pragma unroll
            for (int j = 0; j < 8; ++j) acc[j] += na1 * (float)A1[j];
            #pragma unroll
            for (int j = 0; j < 8; ++j) acc[j] += na2 * (float)A2[j];
            #pragma unroll
            for (int j = 0; j < 8; ++j) acc[j] += na3 * (float)A3[j];
        }
    }
    for (; e + 2 <= cnt; e += 2) {
        int sa   = half ? snp[2 * e + 2] : snp[2 * e];
        float na = __int_as_float(half ? snp[2 * e + 3] : snp[2 * e + 1]);
        h16x8 w = xb[(size_t)sa + chunk];
        #pragma unroll
        for (int j = 0; j < 8; ++j) acc[j] += na * (float)w[j];
    }
    if (e < cnt) {
        int sa = snp[2 * e];
        float na = half ? 0.f : __int_as_float(snp[2 * e + 1]);
        h16x8 w = xb[(size_t)sa + chunk];
        #pragma unroll
        for (int j = 0; j < 8; ++j) acc[j] += na * (float)w[j];
    }
    // fold the two edge-halves
    #pragma unroll
    for (int j = 0; j < 8; ++j) acc[j] += __shfl_xor(acc[j], 32);
    // store (lanes 0..31): acc[j] = A[b_local][c][t], t = (sub&1)*8 + j
    if (lane < 32) {
        int bl = chunk >> 4;
        int sub = chunk & 15;
        int rr = wv * 2 + bl;
        int c = sub >> 1;
        int tpb = (sub & 1) * 4;
        float* rowp = &sAgg[rr * AGG_LD + c * 2];
        #pragma unroll
        for (int k = 0; k < 4; ++k) {
            f32x2 v = {acc[2 * k], acc[2 * k + 1]};
            *(f32x2*)&rowp[(tpb + k) * 16] = v;
        }
    }
    __syncthreads();

    // ---- Phase B: thread -> one (row, o) output ----
    int o = tid & 31, rr = tid >> 5;     // rr = node_in_tile*2 + b_local
    float mz[8], mh[8];
    #pragma unroll
    for (int c = 0; c < 8; ++c) { mz[c] = sMz[c * 32 + o]; mh[c] = sMh[c * 32 + o]; }
    float czo = sCz[o], cho = sCh[o];
    const f32x4* r0 = (const f32x4*)&sAgg[rr * AGG_LD];
    f32x2 o0 = {0.f, 0.f};
    #pragma unroll
    for (int tp = 0; tp < 8; ++tp) {
        f32x4 A0[4];
        #pragma unroll
        for (int k = 0; k < 4; ++k) A0[k] = r0[tp * 4 + k];
        f32x2 uz = {czo, czo}, uh = {cho, cho};
        #pragma unroll
        for (int k = 0; k < 4; ++k) {
            f32x2 pv = A0[k].xy, qv = A0[k].zw;
            uz += pv * mz[2 * k]; uz += qv * mz[2 * k + 1];
            uh += pv * mh[2 * k]; uh += qv * mh[2 * k + 1];
        }
        f32x2 wsp = {sWs[2 * tp], sWs[2 * tp + 1]};
        f32x2 g;
        g.x = gatefn(uz.x, uh.x);
        g.y = gatefn(uz.y, uh.y);
        o0 += wsp * g;
    }
    int b  = bp * 2 + (rr & 1);
    int n2 = tile * NT + (rr >> 1);
    out[((size_t)b * NN + n2) * 32 + o] = o0.x + o0.y;
}

// f32 fallback path — used only if ws_size is too small for the fp16 repack
__global__ __launch_bounds__(256)
void k_main_f32(const float* __restrict__ X,
                const int* __restrict__ offsets, const int* __restrict__ count,
                const float* __restrict__ dinv,
                const int* __restrict__ csr_sn,
                const float* __restrict__ consts,
                float* __restrict__ out) {
    __shared__ float sAgg[NB * 128];
    __shared__ float sMz[256], sMh[256], sCz[32], sCh[32], sWs[16];
    int tid = threadIdx.x;
    int n = blockIdx.x;

    sMz[tid] = consts[tid];
    sMh[tid] = consts[256 + tid];
    if (tid < 32) { sCz[tid] = consts[512 + tid]; sCh[tid] = consts[544 + tid]; }
    if (tid < 16) sWs[tid] = consts[576 + tid];

    int b = tid >> 4, chunk = tid & 15;
    const f32x8* xv = (const f32x8*)X;
    float dn = dinv[n];
    float selfn = dn * dn;
    float acc[8];
    {
        f32x8 w = xv[((size_t)b * NN + n) * 16 + chunk];
        #pragma unroll
        for (int j = 0; j < 8; ++j) acc[j] = selfn * w[j];
    }
    int off = offsets[n], cnt = count[n];
    for (int e = off; e < off + cnt; ++e) {
        int s32 = csr_sn[2 * e];                 // src*32
        float nrm = __int_as_float(csr_sn[2 * e + 1]);
        f32x8 w = xv[(size_t)b * NN * 16 + (size_t)(s32 >> 1) + chunk];
        #pragma unroll
        for (int j = 0; j < 8; ++j) acc[j] += nrm * w[j];
    }
    #pragma unroll
    for (int j = 0; j < 8; ++j) sAgg[tid * 8 + j] = acc[j];
    __syncthreads();

    int o = tid & 31, b0 = tid >> 5;
    float mz[8], mh[8];
    #pragma unroll
    for (int c = 0; c < 8; ++c) { mz[c] = sMz[c * 32 + o]; mh[c] = sMh[c * 32 + o]; }
    float czo = sCz[o], cho = sCh[o];
    float acc0 = 0.f, acc1 = 0.f;
    #pragma unroll
    for (int t = 0; t < 16; ++t) {
        float uz0 = czo, uh0 = cho, uz1 = czo, uh1 = cho;
        #pragma unroll
        for (int c = 0; c < 8; ++c) {
            float a0 = sAgg[b0 * 128 + c * 16 + t];
            float a1 = sAgg[(b0 + 8) * 128 + c * 16 + t];
            uz0 += a0 * mz[c]; uh0 += a0 * mh[c];
            uz1 += a1 * mz[c]; uh1 += a1 * mh[c];
        }
        float w = sWs[t];
        acc0 += w * gatefn(uz0, uh0);
        acc1 += w * gatefn(uz1, uh1);
    }
    out[((size_t)b0 * NN + n) * 32 + o]       = acc0;
    out[((size_t)(b0 + 8) * NN + n) * 32 + o] = acc1;
}

extern "C" void kernel_launch(void* const* d_in, const int* in_sizes, int n_in,
                              void* d_out, int out_size, void* d_ws, size_t ws_size,
                              hipStream_t stream) {
    const float* X    = (const float*)d_in[0];
    const int*   ei   = (const int*)d_in[1];
    const float* ew   = (const float*)d_in[2];
    const float* attn = (const float*)d_in[3];
    const float* Wcz  = (const float*)d_in[4];
    const float* bcz  = (const float*)d_in[5];
    const float* Wlz  = (const float*)d_in[6];
    const float* blz  = (const float*)d_in[7];
    // d_in[8..11] = Wcr,bcr,Wlr,blr — provably unused (R multiplies H0=0)
    const float* Wch  = (const float*)d_in[12];
    const float* bch  = (const float*)d_in[13];
    const float* Wlh  = (const float*)d_in[14];
    const float* blh  = (const float*)d_in[15];
    float* out = (float*)d_out;

    const size_t x2_bytes = (size_t)NN * 256 * 16;   // 40.96 MB fp16 repack
    const size_t small_bytes = (size_t)NN * 4 * 5 + (size_t)NE * 8 + 592 * 4;
    bool use_h = (ws_size >= x2_bytes + small_bytes);

    char* p = (char*)d_ws;
    h16x8* X2 = nullptr;
    if (use_h) { X2 = (h16x8*)p; p += x2_bytes; }
    float* deg      = (float*)p; p += NN * 4;
    int*   count    = (int*)p;   p += NN * 4;   // adjacent to deg: one memset
    float* dinv     = (float*)p; p += NN * 4;
    int*   offsets  = (int*)p;   p += NN * 4;
    int*   fillptr  = (int*)p;   p += NN * 4;
    int*   csr_sn   = (int*)p;   p += (size_t)NE * 8;   // {src*32, norm} pairs
    float* consts   = (float*)p; p += 592 * 4;          // also absorbs ±128B overread

    hipMemsetAsync(deg, 0, (size_t)NN * 8, stream);   // deg + count
    hipLaunchKernelGGL(k_prep, dim3(1280), dim3(256), 0, stream,
                       X, X2, use_h ? 1 : 0, ei, ew, deg, count,
                       attn, Wcz, bcz, Wlz, blz, Wch, bch, Wlh, blh, consts);
    hipLaunchKernelGGL(k_scan, dim3(1), dim3(1024), 0, stream,
                       deg, count, dinv, offsets, fillptr);
    hipLaunchKernelGGL(k_fill, dim3((NE + 255) / 256), dim3(256), 0, stream,
                       ei, ew, dinv, fillptr, csr_sn);
    if (use_h) {
        hipLaunchKernelGGL(k_main_h, dim3((NN / NT) * 8), dim3(256), 0, stream,
                           X2, offsets, count, dinv, csr_sn, consts, out);
    } else {
        hipLaunchKernelGGL(k_main_f32, dim3(NN), dim3(256), 0, stream,
                           X, offsets, count, dinv, csr_sn, consts, out);
    }
}